// Round 3
// baseline (289.490 us; speedup 1.0000x reference)
//
#include <hip/hip_runtime.h>

typedef unsigned short u16;
typedef unsigned long long u64;
typedef __attribute__((ext_vector_type(4))) float f32x4;
typedef __attribute__((ext_vector_type(8))) short s16x8;

#define DEV __device__ __forceinline__

DEV u16 bf16_rne(float f) {
    unsigned u = __builtin_bit_cast(unsigned, f);
    u += 0x7fffu + ((u >> 16) & 1u);
    return (u16)(u >> 16);
}
DEV float bf2f(u16 h) {
    unsigned u = ((unsigned)h) << 16;
    return __builtin_bit_cast(float, u);
}
DEV void gload_lds16(const void* g, void* l) {
    __builtin_amdgcn_global_load_lds((const __attribute__((address_space(1))) void*)g,
                                     (__attribute__((address_space(3))) void*)l, 16, 0, 0);
}

// ---------------- f32 -> bf16 convert (vectorized x4) ----------------
__global__ __launch_bounds__(256)
void cvt_bf16(const float* __restrict__ in, u16* __restrict__ out, int n4) {
    int i = blockIdx.x * 256 + threadIdx.x;
    if (i >= n4) return;
    f32x4 v = ((const f32x4*)in)[i];
    u64 o =  (u64)bf16_rne(v[0])
          | ((u64)bf16_rne(v[1]) << 16)
          | ((u64)bf16_rne(v[2]) << 32)
          | ((u64)bf16_rne(v[3]) << 48);
    ((u64*)out)[i] = o;
}

// ================= 256x128-tile 8-wave GEMM, counted vmcnt pipeline =================
// C(MxN) = A(MxK) * B(NxK)^T [+ bias]. BK=64. 8 waves as 4M x 2N; per-wave 64x64.
// Double-buffered LDS (96 KB), XOR-swizzled rows (T2), counted vmcnt(6) (T4).
// MODE 0: bf16 out + bias. MODE 1: f32 out, no bias.
template<int MODE>
__global__ __launch_bounds__(512, 1)
void gemm_bt2(const u16* __restrict__ A, const u16* __restrict__ B,
              const float* __restrict__ bias, void* __restrict__ Cout,
              int M, int N, int K) {
    __shared__ u16 Abuf[2][256 * 64];
    __shared__ u16 Bbuf[2][128 * 64];
    const int tid = threadIdx.x;
    const int w = tid >> 6, l = tid & 63;
    const int lr = l & 15, lg = l >> 4;
    const int wm = w >> 1, wn = w & 1;
    const int nbn = N >> 7;
    const int bm = blockIdx.x / nbn, bn = blockIdx.x % nbn;
    const int NT = K >> 6;
    const int rsel = l >> 3;
    const int csw = (l & 7) ^ rsel;   // inverse-swizzled source chunk (rule 21)
    const u16* Ag = A + ((size_t)(bm * 256) + rsel) * K + csw * 8;
    const u16* Bg = B + ((size_t)(bn * 128) + rsel) * K + csw * 8;

    f32x4 acc[4][4] = {};

#define STAGE(t, bufi) {                                                              \
        const int k0_ = (t) * 64;                                                     \
        _Pragma("unroll")                                                             \
        for (int j = 0; j < 4; ++j)                                                   \
            gload_lds16(Ag + (size_t)(w * 32 + j * 8) * K + k0_,                      \
                        &Abuf[bufi][(w * 32 + j * 8) * 64]);                          \
        _Pragma("unroll")                                                             \
        for (int j = 0; j < 2; ++j)                                                   \
            gload_lds16(Bg + (size_t)(w * 16 + j * 8) * K + k0_,                      \
                        &Bbuf[bufi][(w * 16 + j * 8) * 64]);                          \
    }

    STAGE(0, 0);
    STAGE(1, 1);

    #pragma unroll 2
    for (int t = 0; t < NT; ++t) {
        const int bufi = t & 1;
        // own tile-t loads landed (each wave waits its own; barrier makes it global)
        if (t + 1 < NT) asm volatile("s_waitcnt vmcnt(6)" ::: "memory");
        else            asm volatile("s_waitcnt vmcnt(0)" ::: "memory");
        __builtin_amdgcn_s_barrier();

        s16x8 af[2][4], bf[2][4];
        #pragma unroll
        for (int ks = 0; ks < 2; ++ks) {
            #pragma unroll
            for (int mi = 0; mi < 4; ++mi) {
                const int row = wm * 64 + mi * 16 + lr;
                const int off = (row * 64 + ks * 32 + lg * 8) ^ ((row & 7) << 3);
                af[ks][mi] = *(const s16x8*)&Abuf[bufi][off];
            }
            #pragma unroll
            for (int ni = 0; ni < 4; ++ni) {
                const int row = wn * 64 + ni * 16 + lr;
                const int off = (row * 64 + ks * 32 + lg * 8) ^ ((row & 7) << 3);
                bf[ks][ni] = *(const s16x8*)&Bbuf[bufi][off];
            }
        }
        asm volatile("s_waitcnt lgkmcnt(0)" ::: "memory");
        __builtin_amdgcn_s_barrier();   // all waves done reading buf -> safe to restage

        if (t + 2 < NT) STAGE(t + 2, bufi);

        __builtin_amdgcn_s_setprio(1);
        #pragma unroll
        for (int ks = 0; ks < 2; ++ks)
            #pragma unroll
            for (int mi = 0; mi < 4; ++mi)
                #pragma unroll
                for (int ni = 0; ni < 4; ++ni)
                    acc[mi][ni] = __builtin_amdgcn_mfma_f32_16x16x32_bf16(af[ks][mi], bf[ks][ni], acc[mi][ni], 0, 0, 0);
        __builtin_amdgcn_s_setprio(0);
    }
#undef STAGE

    #pragma unroll
    for (int ni = 0; ni < 4; ++ni) {
        const int col = bn * 128 + wn * 64 + ni * 16 + lr;
        const float bv = (MODE == 0) ? bias[col] : 0.0f;
        #pragma unroll
        for (int mi = 0; mi < 4; ++mi) {
            #pragma unroll
            for (int r = 0; r < 4; ++r) {
                const int row = bm * 256 + wm * 64 + mi * 16 + lg * 4 + r;
                const float v = acc[mi][ni][r] + bv;
                if (MODE == 0) ((u16*)Cout)[(size_t)row * N + col] = bf16_rne(v);
                else           ((float*)Cout)[(size_t)row * N + col] = v;
            }
        }
    }
}

// ---------------- KV-proj GEMM (128x128, 4-wave), K/V^T split epilogue ----------------
__global__ __launch_bounds__(256)
void gemm_kv(const u16* __restrict__ A, const u16* __restrict__ B,
             const float* __restrict__ bias, void* __restrict__ Cout,
             void* __restrict__ Cout2, int M, int N, int K) {
    __shared__ u16 As[128 * 64];
    __shared__ u16 Bs[128 * 64];
    const int tid = threadIdx.x;
    const int w = tid >> 6, l = tid & 63;
    const int nbn = N >> 7;
    const int bm = blockIdx.x / nbn;
    const int bn = blockIdx.x % nbn;
    const int wr = w >> 1, wc = w & 1;
    const int lr = l & 15, lg = l >> 4;
    const int rowsel = l >> 3, chunk = l & 7;

    f32x4 acc[4][4] = {};

    const u16* Abase = A + (size_t)(bm * 128 + w * 32) * K;
    const u16* Bbase = B + (size_t)(bn * 128 + w * 32) * K;
    u16* AsW = As + (w * 32) * 64;
    u16* BsW = Bs + (w * 32) * 64;

    for (int k0 = 0; k0 < K; k0 += 64) {
        __syncthreads();
        #pragma unroll
        for (int i = 0; i < 4; ++i) {
            gload_lds16(Abase + (size_t)(i * 8 + rowsel) * K + k0 + chunk * 8, AsW + i * 8 * 64);
            gload_lds16(Bbase + (size_t)(i * 8 + rowsel) * K + k0 + chunk * 8, BsW + i * 8 * 64);
        }
        __syncthreads();
        #pragma unroll
        for (int ks = 0; ks < 2; ++ks) {
            s16x8 af[4], bfr[4];
            #pragma unroll
            for (int mi = 0; mi < 4; ++mi)
                af[mi] = *(const s16x8*)(As + (wr * 64 + mi * 16 + lr) * 64 + ks * 32 + lg * 8);
            #pragma unroll
            for (int ni = 0; ni < 4; ++ni)
                bfr[ni] = *(const s16x8*)(Bs + (wc * 64 + ni * 16 + lr) * 64 + ks * 32 + lg * 8);
            #pragma unroll
            for (int mi = 0; mi < 4; ++mi)
                #pragma unroll
                for (int ni = 0; ni < 4; ++ni)
                    acc[mi][ni] = __builtin_amdgcn_mfma_f32_16x16x32_bf16(af[mi], bfr[ni], acc[mi][ni], 0, 0, 0);
        }
    }

    const int row0 = bm * 128 + wr * 64;
    const int col0 = bn * 128 + wc * 64;
    #pragma unroll
    for (int ni = 0; ni < 4; ++ni) {
        const int col = col0 + ni * 16 + lr;
        const float bv = bias[col];
        #pragma unroll
        for (int mi = 0; mi < 4; ++mi) {
            const int bb = row0 >> 11;
            const int s = (row0 & 2047) + mi * 16 + lg * 4;
            float v0 = acc[mi][ni][0] + bv, v1 = acc[mi][ni][1] + bv;
            float v2 = acc[mi][ni][2] + bv, v3 = acc[mi][ni][3] + bv;
            if (col < 256) {
                const int kvh = col >> 7, d = col & 127;
                u16* kp = (u16*)Cout + ((size_t)(bb * 2 + kvh) * 2048 + s) * 128 + d;
                kp[0]   = bf16_rne(v0);
                kp[128] = bf16_rne(v1);
                kp[256] = bf16_rne(v2);
                kp[384] = bf16_rne(v3);
            } else {
                const int kvh = (col - 256) >> 7, d = (col - 256) & 127;
                u64 pk =  (u64)bf16_rne(v0)
                       | ((u64)bf16_rne(v1) << 16)
                       | ((u64)bf16_rne(v2) << 32)
                       | ((u64)bf16_rne(v3) << 48);
                *(u64*)((u16*)Cout2 + ((size_t)(bb * 2 + kvh) * 128 + d) * 2048 + s) = pk;
            }
        }
    }
}

// ---------------- RoPE in-place on bf16, pairs (d, d+64) per 128-head ----------------
template<int NHEADS, int ROWSTRIDE>
__global__ __launch_bounds__(256)
void rope_kernel(u16* __restrict__ t, const float* __restrict__ cosb,
                 const float* __restrict__ sinb, float scale) {
    const int i = blockIdx.x * 256 + threadIdx.x;
    const int d = i & 63;
    const int h = (i >> 6) % NHEADS;
    const int bs = (i >> 6) / NHEADS;
    const int srow = bs & 2047;
    const size_t base = (size_t)bs * ROWSTRIDE + h * 128;
    const float c0 = cosb[srow * 128 + d],      s0 = sinb[srow * 128 + d];
    const float c1 = cosb[srow * 128 + d + 64], s1 = sinb[srow * 128 + d + 64];
    const float t0 = bf2f(t[base + d]);
    const float t1 = bf2f(t[base + d + 64]);
    t[base + d]      = bf16_rne((t0 * c0 - t1 * s0) * scale);
    t[base + d + 64] = bf16_rne((t1 * c1 + t0 * s1) * scale);
}

// ---------------- causal GQA flash attention (single tile / block) ----------------
// grid (32, 32): x -> tile (heavy-first remap), y = b*16 + h. 4 waves x 16 q-rows.
// Scores are in exp2 domain (log2e folded into Q scale). Defer-max THR=11.5 (=8 nats).
__global__ __launch_bounds__(256, 3)
void attn_fwd(const u16* __restrict__ Q, const u16* __restrict__ Kb,
              const u16* __restrict__ VTb, u16* __restrict__ O) {
    __shared__ u16 lds[64 * 128 + 128 * 64 + 4 * 16 * 72];  // 41 KB -> 3 blocks/CU
    u16* Ks = lds;                  // [64 k][128 d], XOR-swizzled
    u16* Vs = lds + 64 * 128;       // [128 d][64 k] (V^T), XOR-swizzled
    u16* Ps = lds + 64 * 128 + 128 * 64;

    const int tid = threadIdx.x, w = tid >> 6, l = tid & 63;
    const int lr = l & 15, lg = l >> 4;
    const int tile = 31 - blockIdx.x;       // heavy blocks dispatched first
    const int bh = blockIdx.y;
    const int b = bh >> 4, h = bh & 15;
    const int kvh = h >> 3;
    const u16* Kg = Kb + (size_t)(b * 2 + kvh) * 2048 * 128;
    const u16* Vg = VTb + (size_t)(b * 2 + kvh) * 128 * 2048;
    u16* Pw = Ps + w * (16 * 72);

    const int qrow = tile * 64 + w * 16 + lr;   // this lane's q column
    s16x8 qf[4];
    {
        const u16* Qrow = Q + ((size_t)(b * 2048 + qrow) * 2048 + h * 128);
        #pragma unroll
        for (int ks = 0; ks < 4; ++ks)
            qf[ks] = *(const s16x8*)(Qrow + ks * 32 + lg * 8);
    }

    float m = -1e30f, lsum = 0.0f;
    f32x4 oacc[8] = {};

    auto iter = [&](int kt, bool domask) {
        __syncthreads();  // previous iteration's LDS reads complete
        // stage K [64][128]: linear LDS dest, inverse-swizzled global source
        #pragma unroll
        for (int i = 0; i < 4; ++i) {
            const int row = (w * 4 + i) * 4 + lg;
            const int srcoff = (lr * 16) ^ ((row & 7) << 4);
            gload_lds16((const char*)Kg + (size_t)(kt * 64 + row) * 256 + srcoff,
                        (char*)Ks + (w * 4 + i) * 1024);
        }
        // stage V^T [128][64]
        #pragma unroll
        for (int i = 0; i < 4; ++i) {
            const int d = (w * 4 + i) * 8 + (l >> 3);
            const int srcoff = ((l & 7) * 16) ^ ((d & 7) << 4);
            gload_lds16((const char*)Vg + (size_t)d * 4096 + (size_t)kt * 128 + srcoff,
                        (char*)Vs + (w * 4 + i) * 1024);
        }
        __syncthreads();  // staging complete

        // ---- swapped QK^T: sc[kf] rows k = kf*16+lg*4+r, col q = lr
        f32x4 sc[4] = {};
        __builtin_amdgcn_s_setprio(1);
        #pragma unroll
        for (int ks = 0; ks < 4; ++ks) {
            #pragma unroll
            for (int kf = 0; kf < 4; ++kf) {
                const int row = kf * 16 + lr;
                const int boff = (row * 256 + ks * 64 + lg * 16) ^ ((row & 7) << 4);
                s16x8 kfr = *(const s16x8*)((const char*)Ks + boff);
                sc[kf] = __builtin_amdgcn_mfma_f32_16x16x32_bf16(kfr, qf[ks], sc[kf], 0, 0, 0);
            }
        }
        __builtin_amdgcn_s_setprio(0);

        // ---- causal mask (diagonal tile only) + online softmax, exp2 domain
        float mx = m;
        #pragma unroll
        for (int kf = 0; kf < 4; ++kf)
            #pragma unroll
            for (int r = 0; r < 4; ++r) {
                float s = sc[kf][r];
                if (domask) {
                    const int kpos = kt * 64 + kf * 16 + lg * 4 + r;
                    s = (kpos <= qrow) ? s : -1e30f;
                    sc[kf][r] = s;
                }
                mx = fmaxf(mx, s);
            }
        mx = fmaxf(mx, __shfl_xor(mx, 16, 64));
        mx = fmaxf(mx, __shfl_xor(mx, 32, 64));
        const bool need = __any(mx > m + 11.5f);   // T13 defer-max (8 nats in log2)
        float corr = 1.0f;
        if (need) { corr = exp2f(m - mx); m = mx; }
        float rs = 0.0f;
        #pragma unroll
        for (int kf = 0; kf < 4; ++kf)
            #pragma unroll
            for (int r = 0; r < 4; ++r) {
                const float p = exp2f(sc[kf][r] - m);
                sc[kf][r] = p;
                rs += p;
            }
        rs += __shfl_xor(rs, 16, 64);
        rs += __shfl_xor(rs, 32, 64);
        lsum = lsum * corr + rs;
        if (need) {
            float corrq[4];
            #pragma unroll
            for (int r = 0; r < 4; ++r)
                corrq[r] = __shfl(corr, lg * 4 + r, 64);
            #pragma unroll
            for (int nd = 0; nd < 8; ++nd)
                #pragma unroll
                for (int r = 0; r < 4; ++r)
                    oacc[nd][r] *= corrq[r];
        }

        // ---- P -> wave-private padded LDS [16][72] (same-wave, no barrier)
        #pragma unroll
        for (int kf = 0; kf < 4; ++kf) {
            u64 pkd =  (u64)bf16_rne(sc[kf][0])
                    | ((u64)bf16_rne(sc[kf][1]) << 16)
                    | ((u64)bf16_rne(sc[kf][2]) << 32)
                    | ((u64)bf16_rne(sc[kf][3]) << 48);
            *(u64*)((char*)Pw + lr * 144 + kf * 32 + lg * 8) = pkd;
        }
        s16x8 pf[2];
        #pragma unroll
        for (int ksb = 0; ksb < 2; ++ksb)
            pf[ksb] = *(const s16x8*)((char*)Pw + lr * 144 + ksb * 64 + lg * 16);

        // ---- PV: oacc[nd] rows q = lg*4+r, col d = nd*16+lr
        __builtin_amdgcn_s_setprio(1);
        #pragma unroll
        for (int ksb = 0; ksb < 2; ++ksb)
            #pragma unroll
            for (int nd = 0; nd < 8; ++nd) {
                const int row = nd * 16 + lr;
                const int boff = (row * 128 + ksb * 64 + lg * 16) ^ ((row & 7) << 4);
                s16x8 vf = *(const s16x8*)((const char*)Vs + boff);
                oacc[nd] = __builtin_amdgcn_mfma_f32_16x16x32_bf16(pf[ksb], vf, oacc[nd], 0, 0, 0);
            }
        __builtin_amdgcn_s_setprio(0);
    };

    for (int kt = 0; kt < tile; ++kt) iter(kt, false);
    iter(tile, true);

    // ---- epilogue: normalize (inv lives in lane lr = q-row), write bf16
    const float inv = 1.0f / lsum;
    float invq[4];
    #pragma unroll
    for (int r = 0; r < 4; ++r)
        invq[r] = __shfl(inv, lg * 4 + r, 64);
    #pragma unroll
    for (int r = 0; r < 4; ++r) {
        const int q = tile * 64 + w * 16 + lg * 4 + r;
        u16* orow = O + ((size_t)(b * 2048 + q) * 2048 + h * 128);
        #pragma unroll
        for (int nd = 0; nd < 8; ++nd)
            orow[nd * 16 + lr] = bf16_rne(oacc[nd][r] * invq[r]);
    }
}

// ---------------- launch ----------------
extern "C" void kernel_launch(void* const* d_in, const int* in_sizes, int n_in,
                              void* d_out, int out_size, void* d_ws, size_t ws_size,
                              hipStream_t stream) {
    const float* x    = (const float*)d_in[0];
    const float* cosb = (const float*)d_in[1];
    const float* sinb = (const float*)d_in[2];
    const float* q_w  = (const float*)d_in[3];
    const float* q_b  = (const float*)d_in[4];
    const float* kv_w = (const float*)d_in[5];
    const float* kv_b = (const float*)d_in[6];
    const float* o_w  = (const float*)d_in[7];
    float* out = (float*)d_out;

    char* p = (char*)d_ws;
    u16* x_bf   = (u16*)p; p += (size_t)4096 * 2048 * 2;
    u16* qw_bf  = (u16*)p; p += (size_t)2048 * 2048 * 2;
    u16* kvw_bf = (u16*)p; p += (size_t)512 * 2048 * 2;
    u16* ow_bf  = (u16*)p; p += (size_t)2048 * 2048 * 2;
    u16* q_bf   = (u16*)p; p += (size_t)4096 * 2048 * 2;
    u16* k_bf   = (u16*)p; p += (size_t)4 * 2048 * 128 * 2;   // [b][kvh][s][d]
    u16* vt_bf  = (u16*)p; p += (size_t)4 * 128 * 2048 * 2;   // [b][kvh][d][s]
    u16* at_bf  = (u16*)p; p += (size_t)4096 * 2048 * 2;

    cvt_bf16<<<8192, 256, 0, stream>>>(x,    x_bf,   4096 * 2048 / 4);
    cvt_bf16<<<4096, 256, 0, stream>>>(q_w,  qw_bf,  2048 * 2048 / 4);
    cvt_bf16<<<1024, 256, 0, stream>>>(kv_w, kvw_bf,  512 * 2048 / 4);
    cvt_bf16<<<4096, 256, 0, stream>>>(o_w,  ow_bf,  2048 * 2048 / 4);

    gemm_bt2<0><<<dim3(16 * 16), 512, 0, stream>>>(x_bf, qw_bf, q_b, q_bf, 4096, 2048, 2048);
    gemm_kv<<<dim3(32 * 4), 256, 0, stream>>>(x_bf, kvw_bf, kv_b, k_bf, vt_bf, 4096, 512, 2048);

    // 1/sqrt(128) * log2(e): scores in exp2 domain
    const float qk_scale2 = 0.12751744517764862f;
    rope_kernel<16, 2048><<<16384, 256, 0, stream>>>(q_bf, cosb, sinb, qk_scale2);
    rope_kernel<1, 128><<<2048, 256, 0, stream>>>(k_bf, cosb, sinb, 1.0f);

    attn_fwd<<<dim3(32, 32), 256, 0, stream>>>(q_bf, k_bf, vt_bf, at_bf);

    gemm_bt2<1><<<dim3(16 * 16), 512, 0, stream>>>(at_bf, ow_bf, nullptr, out, 4096, 2048, 2048);
}

// Round 4
// 236.204 us; speedup vs baseline: 1.2256x; 1.2256x over previous
//
#include <hip/hip_runtime.h>

typedef unsigned short u16;
typedef unsigned long long u64;
typedef __attribute__((ext_vector_type(4))) float f32x4;
typedef __attribute__((ext_vector_type(8))) short s16x8;

#define DEV __device__ __forceinline__

DEV u16 bf16_rne(float f) {
    unsigned u = __builtin_bit_cast(unsigned, f);
    u += 0x7fffu + ((u >> 16) & 1u);
    return (u16)(u >> 16);
}
DEV float bf2f(u16 h) {
    unsigned u = ((unsigned)h) << 16;
    return __builtin_bit_cast(float, u);
}
DEV void gload_lds16(const void* g, void* l) {
    __builtin_amdgcn_global_load_lds((const __attribute__((address_space(1))) void*)g,
                                     (__attribute__((address_space(3))) void*)l, 16, 0, 0);
}

// ---------------- f32 -> bf16 convert (vectorized x4) ----------------
__global__ __launch_bounds__(256)
void cvt_bf16(const float* __restrict__ in, u16* __restrict__ out, int n4) {
    int i = blockIdx.x * 256 + threadIdx.x;
    if (i >= n4) return;
    f32x4 v = ((const f32x4*)in)[i];
    u64 o =  (u64)bf16_rne(v[0])
          | ((u64)bf16_rne(v[1]) << 16)
          | ((u64)bf16_rne(v[2]) << 32)
          | ((u64)bf16_rne(v[3]) << 48);
    ((u64*)out)[i] = o;
}

// ================= 256x128-tile 8-wave GEMM, counted vmcnt pipeline =================
// C(MxN) = A(MxK) * B(NxK)^T [+ bias]. BK=64. 8 waves as 4M x 2N; per-wave 64x64.
// Double-buffered LDS (96 KB), XOR-swizzled rows (T2), counted vmcnt(6) (T4).
// MODE 0: bf16 out + bias. MODE 1: f32 out, no bias.
template<int MODE>
__global__ __launch_bounds__(512, 1)
void gemm_bt2(const u16* __restrict__ A, const u16* __restrict__ B,
              const float* __restrict__ bias, void* __restrict__ Cout,
              int M, int N, int K) {
    __shared__ u16 Abuf[2][256 * 64];
    __shared__ u16 Bbuf[2][128 * 64];
    const int tid = threadIdx.x;
    const int w = tid >> 6, l = tid & 63;
    const int lr = l & 15, lg = l >> 4;
    const int wm = w >> 1, wn = w & 1;
    const int nbn = N >> 7;
    const int bm = blockIdx.x / nbn, bn = blockIdx.x % nbn;
    const int NT = K >> 6;
    const int rsel = l >> 3;
    const int csw = (l & 7) ^ rsel;   // inverse-swizzled source chunk (rule 21)
    const u16* Ag = A + ((size_t)(bm * 256) + rsel) * K + csw * 8;
    const u16* Bg = B + ((size_t)(bn * 128) + rsel) * K + csw * 8;

    f32x4 acc[4][4] = {};

#define STAGE(t, bufi) {                                                              \
        const int k0_ = (t) * 64;                                                     \
        _Pragma("unroll")                                                             \
        for (int j = 0; j < 4; ++j)                                                   \
            gload_lds16(Ag + (size_t)(w * 32 + j * 8) * K + k0_,                      \
                        &Abuf[bufi][(w * 32 + j * 8) * 64]);                          \
        _Pragma("unroll")                                                             \
        for (int j = 0; j < 2; ++j)                                                   \
            gload_lds16(Bg + (size_t)(w * 16 + j * 8) * K + k0_,                      \
                        &Bbuf[bufi][(w * 16 + j * 8) * 64]);                          \
    }

    STAGE(0, 0);
    STAGE(1, 1);

    #pragma unroll 2
    for (int t = 0; t < NT; ++t) {
        const int bufi = t & 1;
        if (t + 1 < NT) asm volatile("s_waitcnt vmcnt(6)" ::: "memory");
        else            asm volatile("s_waitcnt vmcnt(0)" ::: "memory");
        __builtin_amdgcn_s_barrier();

        s16x8 af[2][4], bf[2][4];
        #pragma unroll
        for (int ks = 0; ks < 2; ++ks) {
            #pragma unroll
            for (int mi = 0; mi < 4; ++mi) {
                const int row = wm * 64 + mi * 16 + lr;
                const int off = (row * 64 + ks * 32 + lg * 8) ^ ((row & 7) << 3);
                af[ks][mi] = *(const s16x8*)&Abuf[bufi][off];
            }
            #pragma unroll
            for (int ni = 0; ni < 4; ++ni) {
                const int row = wn * 64 + ni * 16 + lr;
                const int off = (row * 64 + ks * 32 + lg * 8) ^ ((row & 7) << 3);
                bf[ks][ni] = *(const s16x8*)&Bbuf[bufi][off];
            }
        }
        asm volatile("s_waitcnt lgkmcnt(0)" ::: "memory");
        __builtin_amdgcn_s_barrier();   // all waves done reading buf -> safe to restage

        if (t + 2 < NT) STAGE(t + 2, bufi);

        __builtin_amdgcn_s_setprio(1);
        #pragma unroll
        for (int ks = 0; ks < 2; ++ks)
            #pragma unroll
            for (int mi = 0; mi < 4; ++mi)
                #pragma unroll
                for (int ni = 0; ni < 4; ++ni)
                    acc[mi][ni] = __builtin_amdgcn_mfma_f32_16x16x32_bf16(af[ks][mi], bf[ks][ni], acc[mi][ni], 0, 0, 0);
        __builtin_amdgcn_s_setprio(0);
    }
#undef STAGE

    #pragma unroll
    for (int ni = 0; ni < 4; ++ni) {
        const int col = bn * 128 + wn * 64 + ni * 16 + lr;
        const float bv = (MODE == 0) ? bias[col] : 0.0f;
        #pragma unroll
        for (int mi = 0; mi < 4; ++mi) {
            #pragma unroll
            for (int r = 0; r < 4; ++r) {
                const int row = bm * 256 + wm * 64 + mi * 16 + lg * 4 + r;
                const float v = acc[mi][ni][r] + bv;
                if (MODE == 0) ((u16*)Cout)[(size_t)row * N + col] = bf16_rne(v);
                else           ((float*)Cout)[(size_t)row * N + col] = v;
            }
        }
    }
}

// ---------------- KV-proj GEMM (128x128, 4-wave), K/V^T split epilogue ----------------
__global__ __launch_bounds__(256)
void gemm_kv(const u16* __restrict__ A, const u16* __restrict__ B,
             const float* __restrict__ bias, void* __restrict__ Cout,
             void* __restrict__ Cout2, int M, int N, int K) {
    __shared__ u16 As[128 * 64];
    __shared__ u16 Bs[128 * 64];
    const int tid = threadIdx.x;
    const int w = tid >> 6, l = tid & 63;
    const int nbn = N >> 7;
    const int bm = blockIdx.x / nbn;
    const int bn = blockIdx.x % nbn;
    const int wr = w >> 1, wc = w & 1;
    const int lr = l & 15, lg = l >> 4;
    const int rowsel = l >> 3, chunk = l & 7;

    f32x4 acc[4][4] = {};

    const u16* Abase = A + (size_t)(bm * 128 + w * 32) * K;
    const u16* Bbase = B + (size_t)(bn * 128 + w * 32) * K;
    u16* AsW = As + (w * 32) * 64;
    u16* BsW = Bs + (w * 32) * 64;

    for (int k0 = 0; k0 < K; k0 += 64) {
        __syncthreads();
        #pragma unroll
        for (int i = 0; i < 4; ++i) {
            gload_lds16(Abase + (size_t)(i * 8 + rowsel) * K + k0 + chunk * 8, AsW + i * 8 * 64);
            gload_lds16(Bbase + (size_t)(i * 8 + rowsel) * K + k0 + chunk * 8, BsW + i * 8 * 64);
        }
        __syncthreads();
        #pragma unroll
        for (int ks = 0; ks < 2; ++ks) {
            s16x8 af[4], bfr[4];
            #pragma unroll
            for (int mi = 0; mi < 4; ++mi)
                af[mi] = *(const s16x8*)(As + (wr * 64 + mi * 16 + lr) * 64 + ks * 32 + lg * 8);
            #pragma unroll
            for (int ni = 0; ni < 4; ++ni)
                bfr[ni] = *(const s16x8*)(Bs + (wc * 64 + ni * 16 + lr) * 64 + ks * 32 + lg * 8);
            #pragma unroll
            for (int mi = 0; mi < 4; ++mi)
                #pragma unroll
                for (int ni = 0; ni < 4; ++ni)
                    acc[mi][ni] = __builtin_amdgcn_mfma_f32_16x16x32_bf16(af[mi], bfr[ni], acc[mi][ni], 0, 0, 0);
        }
    }

    const int row0 = bm * 128 + wr * 64;
    const int col0 = bn * 128 + wc * 64;
    #pragma unroll
    for (int ni = 0; ni < 4; ++ni) {
        const int col = col0 + ni * 16 + lr;
        const float bv = bias[col];
        #pragma unroll
        for (int mi = 0; mi < 4; ++mi) {
            const int bb = row0 >> 11;
            const int s = (row0 & 2047) + mi * 16 + lg * 4;
            float v0 = acc[mi][ni][0] + bv, v1 = acc[mi][ni][1] + bv;
            float v2 = acc[mi][ni][2] + bv, v3 = acc[mi][ni][3] + bv;
            if (col < 256) {
                const int kvh = col >> 7, d = col & 127;
                u16* kp = (u16*)Cout + ((size_t)(bb * 2 + kvh) * 2048 + s) * 128 + d;
                kp[0]   = bf16_rne(v0);
                kp[128] = bf16_rne(v1);
                kp[256] = bf16_rne(v2);
                kp[384] = bf16_rne(v3);
            } else {
                const int kvh = (col - 256) >> 7, d = (col - 256) & 127;
                u64 pk =  (u64)bf16_rne(v0)
                       | ((u64)bf16_rne(v1) << 16)
                       | ((u64)bf16_rne(v2) << 32)
                       | ((u64)bf16_rne(v3) << 48);
                *(u64*)((u16*)Cout2 + ((size_t)(bb * 2 + kvh) * 128 + d) * 2048 + s) = pk;
            }
        }
    }
}

// ---------------- RoPE in-place on bf16, pairs (d, d+64) per 128-head ----------------
template<int NHEADS, int ROWSTRIDE>
__global__ __launch_bounds__(256)
void rope_kernel(u16* __restrict__ t, const float* __restrict__ cosb,
                 const float* __restrict__ sinb, float scale) {
    const int i = blockIdx.x * 256 + threadIdx.x;
    const int d = i & 63;
    const int h = (i >> 6) % NHEADS;
    const int bs = (i >> 6) / NHEADS;
    const int srow = bs & 2047;
    const size_t base = (size_t)bs * ROWSTRIDE + h * 128;
    const float c0 = cosb[srow * 128 + d],      s0 = sinb[srow * 128 + d];
    const float c1 = cosb[srow * 128 + d + 64], s1 = sinb[srow * 128 + d + 64];
    const float t0 = bf2f(t[base + d]);
    const float t1 = bf2f(t[base + d + 64]);
    t[base + d]      = bf16_rne((t0 * c0 - t1 * s0) * scale);
    t[base + d + 64] = bf16_rne((t1 * c1 + t0 * s1) * scale);
}

// ---------------- causal GQA flash attention (swapped-QK, paired tiles) ----------------
// grid (16, 32): x = pair index pi (tiles pi, 31-pi: 33 K-iters total -> perfectly
// balanced). y = b*16 + h. 4 waves x 16 q-rows. Double-buffered K/V in LDS with
// counted vmcnt(8) prefetch; raw s_barrier (no vmcnt drain) in the hot loop.
// Scores in exp2 domain (log2e folded into Q scale). Defer-max THR=11.5 (~8 nats).
__global__ __launch_bounds__(256, 2)
void attn_fwd(const u16* __restrict__ Q, const u16* __restrict__ Kb,
              const u16* __restrict__ VTb, u16* __restrict__ O) {
    // K dbuf 2x16KB + V^T dbuf 2x16KB + P 9KB = 73 KB -> 2 blocks/CU
    __shared__ u16 lds[2 * 64 * 128 + 2 * 128 * 64 + 4 * 16 * 72];
    u16* Ps = lds + 32768;

    const int tid = threadIdx.x, w = tid >> 6, l = tid & 63;
    const int lr = l & 15, lg = l >> 4;
    const int pi = blockIdx.x;
    const int bh = blockIdx.y;
    const int b = bh >> 4, h = bh & 15;
    const int kvh = h >> 3;
    const u16* Kg = Kb + (size_t)(b * 2 + kvh) * 2048 * 128;
    const u16* Vg = VTb + (size_t)(b * 2 + kvh) * 128 * 2048;
    u16* Pw = Ps + w * (16 * 72);

    // stage K[64][128] + V^T[128][64] for K-tile kt into buffer (kt&1).
    // Linear LDS dest, inverse-swizzled global source (rule 21). 8 loads/wave.
    auto stage = [&](int kt) {
        u16* Kd = lds + (kt & 1) * 8192;
        u16* Vd = lds + 16384 + (kt & 1) * 8192;
        #pragma unroll
        for (int i = 0; i < 4; ++i) {
            const int row = (w * 4 + i) * 4 + lg;
            const int srcoff = (lr * 16) ^ ((row & 7) << 4);
            gload_lds16((const char*)Kg + (size_t)(kt * 64 + row) * 256 + srcoff,
                        (char*)Kd + (w * 4 + i) * 1024);
        }
        #pragma unroll
        for (int i = 0; i < 4; ++i) {
            const int d = (w * 4 + i) * 8 + (l >> 3);
            const int srcoff = ((l & 7) * 16) ^ ((d & 7) << 4);
            gload_lds16((const char*)Vg + (size_t)d * 4096 + (size_t)kt * 128 + srcoff,
                        (char*)Vd + (w * 4 + i) * 1024);
        }
    };

    #pragma unroll 1
    for (int t = 0; t < 2; ++t) {
        const int tile = t ? (31 - pi) : pi;
        const int qrow = tile * 64 + w * 16 + lr;   // this lane's q column
        s16x8 qf[4];
        {
            const u16* Qrow = Q + ((size_t)(b * 2048 + qrow) * 2048 + h * 128);
            #pragma unroll
            for (int ks = 0; ks < 4; ++ks)
                qf[ks] = *(const s16x8*)(Qrow + ks * 32 + lg * 8);
        }

        float m = -1e30f, lsum = 0.0f;
        f32x4 oacc[8] = {};

        const int ktend = tile + 1;
        __syncthreads();            // tile boundary: all prior LDS reads done
        stage(0);

        #pragma unroll 1
        for (int kt = 0; kt < ktend; ++kt) {
            const u16* Ks = lds + (kt & 1) * 8192;
            const u16* Vs = lds + 16384 + (kt & 1) * 8192;
            if (kt + 1 < ktend) {
                stage(kt + 1);      // prefetch next tile into other buffer
                asm volatile("s_waitcnt vmcnt(8)" ::: "memory");  // tile-kt landed
            } else {
                asm volatile("s_waitcnt vmcnt(0)" ::: "memory");
            }
            __builtin_amdgcn_s_barrier();   // raw: vmcnt(8) stays in flight

            // ---- swapped QK^T: sc[kf] rows k = kf*16+lg*4+r, col q = lr
            f32x4 sc[4] = {};
            __builtin_amdgcn_s_setprio(1);
            #pragma unroll
            for (int ks = 0; ks < 4; ++ks) {
                #pragma unroll
                for (int kf = 0; kf < 4; ++kf) {
                    const int row = kf * 16 + lr;
                    const int boff = (row * 256 + ks * 64 + lg * 16) ^ ((row & 7) << 4);
                    s16x8 kfr = *(const s16x8*)((const char*)Ks + boff);
                    sc[kf] = __builtin_amdgcn_mfma_f32_16x16x32_bf16(kfr, qf[ks], sc[kf], 0, 0, 0);
                }
            }
            __builtin_amdgcn_s_setprio(0);

            // ---- causal mask (diagonal tile only) + online softmax, exp2 domain
            const bool domask = (kt == tile);
            float mx = m;
            #pragma unroll
            for (int kf = 0; kf < 4; ++kf)
                #pragma unroll
                for (int r = 0; r < 4; ++r) {
                    float s = sc[kf][r];
                    if (domask) {
                        const int kpos = kt * 64 + kf * 16 + lg * 4 + r;
                        s = (kpos <= qrow) ? s : -1e30f;
                        sc[kf][r] = s;
                    }
                    mx = fmaxf(mx, s);
                }
            mx = fmaxf(mx, __shfl_xor(mx, 16, 64));
            mx = fmaxf(mx, __shfl_xor(mx, 32, 64));
            const bool need = __any(mx > m + 11.5f);   // T13 defer-max
            float corr = 1.0f;
            if (need) { corr = exp2f(m - mx); m = mx; }
            float rs = 0.0f;
            #pragma unroll
            for (int kf = 0; kf < 4; ++kf)
                #pragma unroll
                for (int r = 0; r < 4; ++r) {
                    const float p = exp2f(sc[kf][r] - m);
                    sc[kf][r] = p;
                    rs += p;
                }
            rs += __shfl_xor(rs, 16, 64);
            rs += __shfl_xor(rs, 32, 64);
            lsum = lsum * corr + rs;
            if (need) {
                float corrq[4];
                #pragma unroll
                for (int r = 0; r < 4; ++r)
                    corrq[r] = __shfl(corr, lg * 4 + r, 64);
                #pragma unroll
                for (int nd = 0; nd < 8; ++nd)
                    #pragma unroll
                    for (int r = 0; r < 4; ++r)
                        oacc[nd][r] *= corrq[r];
            }

            // ---- P -> wave-private padded LDS [16][72] (same-wave, no barrier)
            #pragma unroll
            for (int kf = 0; kf < 4; ++kf) {
                u64 pkd =  (u64)bf16_rne(sc[kf][0])
                        | ((u64)bf16_rne(sc[kf][1]) << 16)
                        | ((u64)bf16_rne(sc[kf][2]) << 32)
                        | ((u64)bf16_rne(sc[kf][3]) << 48);
                *(u64*)((char*)Pw + lr * 144 + kf * 32 + lg * 8) = pkd;
            }
            s16x8 pf[2];
            #pragma unroll
            for (int ksb = 0; ksb < 2; ++ksb)
                pf[ksb] = *(const s16x8*)((char*)Pw + lr * 144 + ksb * 64 + lg * 16);

            // ---- PV: oacc[nd] rows q = lg*4+r, col d = nd*16+lr
            __builtin_amdgcn_s_setprio(1);
            #pragma unroll
            for (int ksb = 0; ksb < 2; ++ksb)
                #pragma unroll
                for (int nd = 0; nd < 8; ++nd) {
                    const int row = nd * 16 + lr;
                    const int boff = (row * 128 + ksb * 64 + lg * 16) ^ ((row & 7) << 4);
                    s16x8 vf = *(const s16x8*)((const char*)Vs + boff);
                    oacc[nd] = __builtin_amdgcn_mfma_f32_16x16x32_bf16(pf[ksb], vf, oacc[nd], 0, 0, 0);
                }
            __builtin_amdgcn_s_setprio(0);

            // reads of buf(kt&1) complete before next iter's stage lands there
            asm volatile("s_waitcnt lgkmcnt(0)" ::: "memory");
            __builtin_amdgcn_s_barrier();
        }

        // ---- epilogue: normalize (inv lives in lane lr = q-row), write bf16
        const float inv = 1.0f / lsum;
        float invq[4];
        #pragma unroll
        for (int r = 0; r < 4; ++r)
            invq[r] = __shfl(inv, lg * 4 + r, 64);
        #pragma unroll
        for (int r = 0; r < 4; ++r) {
            const int q = tile * 64 + w * 16 + lg * 4 + r;
            u16* orow = O + ((size_t)(b * 2048 + q) * 2048 + h * 128);
            #pragma unroll
            for (int nd = 0; nd < 8; ++nd)
                orow[nd * 16 + lr] = bf16_rne(oacc[nd][r] * invq[r]);
        }
    }
}

// ---------------- launch ----------------
extern "C" void kernel_launch(void* const* d_in, const int* in_sizes, int n_in,
                              void* d_out, int out_size, void* d_ws, size_t ws_size,
                              hipStream_t stream) {
    const float* x    = (const float*)d_in[0];
    const float* cosb = (const float*)d_in[1];
    const float* sinb = (const float*)d_in[2];
    const float* q_w  = (const float*)d_in[3];
    const float* q_b  = (const float*)d_in[4];
    const float* kv_w = (const float*)d_in[5];
    const float* kv_b = (const float*)d_in[6];
    const float* o_w  = (const float*)d_in[7];
    float* out = (float*)d_out;

    char* p = (char*)d_ws;
    u16* x_bf   = (u16*)p; p += (size_t)4096 * 2048 * 2;
    u16* qw_bf  = (u16*)p; p += (size_t)2048 * 2048 * 2;
    u16* kvw_bf = (u16*)p; p += (size_t)512 * 2048 * 2;
    u16* ow_bf  = (u16*)p; p += (size_t)2048 * 2048 * 2;
    u16* q_bf   = (u16*)p; p += (size_t)4096 * 2048 * 2;
    u16* k_bf   = (u16*)p; p += (size_t)4 * 2048 * 128 * 2;   // [b][kvh][s][d]
    u16* vt_bf  = (u16*)p; p += (size_t)4 * 128 * 2048 * 2;   // [b][kvh][d][s]
    u16* at_bf  = (u16*)p; p += (size_t)4096 * 2048 * 2;

    cvt_bf16<<<8192, 256, 0, stream>>>(x,    x_bf,   4096 * 2048 / 4);
    cvt_bf16<<<4096, 256, 0, stream>>>(q_w,  qw_bf,  2048 * 2048 / 4);
    cvt_bf16<<<1024, 256, 0, stream>>>(kv_w, kvw_bf,  512 * 2048 / 4);
    cvt_bf16<<<4096, 256, 0, stream>>>(o_w,  ow_bf,  2048 * 2048 / 4);

    gemm_bt2<0><<<dim3(16 * 16), 512, 0, stream>>>(x_bf, qw_bf, q_b, q_bf, 4096, 2048, 2048);
    gemm_kv<<<dim3(32 * 4), 256, 0, stream>>>(x_bf, kvw_bf, kv_b, k_bf, vt_bf, 4096, 512, 2048);

    // 1/sqrt(128) * log2(e): scores in exp2 domain
    const float qk_scale2 = 0.12751744517764862f;
    rope_kernel<16, 2048><<<16384, 256, 0, stream>>>(q_bf, cosb, sinb, qk_scale2);
    rope_kernel<1, 128><<<2048, 256, 0, stream>>>(k_bf, cosb, sinb, 1.0f);

    attn_fwd<<<dim3(16, 32), 256, 0, stream>>>(q_bf, k_bf, vt_bf, at_bf);

    gemm_bt2<1><<<dim3(16 * 16), 512, 0, stream>>>(at_bf, ow_bf, nullptr, out, 4096, 2048, 2048);
}